// Round 8
// baseline (176.601 us; speedup 1.0000x reference)
//
#include <hip/hip_runtime.h>

// bicon_loss R14: byte reduction WITH parallelism (fix R13's occupancy collapse).
// R13 post-mortem: 64us (worse). VGPR=184 -> 2 waves/SIMD, 1936 waves total,
// 4-row serial chain -> request throughput fell to 2.3 TB/s (below R6's 4.3!).
// R13 tested "no latency hiding", not the byte lever. Model: per-CU
// outstanding-miss cap ~8 wave-loads x ~1100cy -> ~4.4 TB/s pattern wall
// (m13 copy does 6.3, so not a system wall). Throughput scales with request
// bytes x resident waves. R14: RPT=2 strips (968 blocks, 3872 waves),
// sequential q-batches + 14-quad sigmoid working set to fit VGPR<=128 under
// __launch_bounds__(256,4) -> 16 waves/CU, half R13's serial chain,
// 80 B/px requests (158 MB, -20% vs R6).
// Tripwires: VGPR<=128, WRITE_SIZE ~31KB (spill canary). Prediction: main
// 46 -> ~36-39us. If flat with VGPR<=128: byte lever falsified.

#define EPSF 1e-7f

constexpr int B_ = 16, H = 352, W = 352;
constexpr int HW = H * W;          // 123904
constexpr int W4 = W / 4;          // 88 quads per row
constexpr int RPT = 2;             // rows per thread
constexpr int STRIPS = H / RPT;    // 176
constexpr int SPB = STRIPS * W4;   // 15488 threads per image (242 waves, exact)
constexpr int NT = B_ * SPB;       // 247808
constexpr int BLK = 256;
constexpr int NBLK = NT / BLK;     // 968

typedef float f4 __attribute__((ext_vector_type(4)));
typedef int   i4 __attribute__((ext_vector_type(4)));

__device__ __forceinline__ float rcpf(float x) { return __builtin_amdgcn_rcpf(x); }
__device__ __forceinline__ float sigf(float x) { return rcpf(1.0f + __expf(-x)); }

__device__ __forceinline__ f4 sigmoid4(f4 x) {
    f4 r;
    r.x = rcpf(1.0f + __expf(-x.x));
    r.y = rcpf(1.0f + __expf(-x.y));
    r.z = rcpf(1.0f + __expf(-x.z));
    r.w = rcpf(1.0f + __expf(-x.w));
    return r;
}
__device__ __forceinline__ f4 max4(f4 a, f4 b) {
    f4 r; r.x=fmaxf(a.x,b.x); r.y=fmaxf(a.y,b.y); r.z=fmaxf(a.z,b.z); r.w=fmaxf(a.w,b.w); return r;
}
__device__ __forceinline__ f4 min4(f4 a, f4 b) {
    f4 r; r.x=fminf(a.x,b.x); r.y=fminf(a.y,b.y); r.z=fminf(a.z,b.z); r.w=fminf(a.w,b.w); return r;
}
__device__ __forceinline__ f4 sel4(i4 q, f4 a, f4 b) {
    f4 r; r.x=q.x?a.x:b.x; r.y=q.y?a.y:b.y; r.z=q.z?a.z:b.z; r.w=q.w?a.w:b.w; return r;
}
__device__ __forceinline__ f4 ld4(const float* p) { return *(const f4*)p; }
__device__ __forceinline__ i4 ldi4(const int* p)  { return *(const i4*)p; }

// shifted-quad builders from already-sigmoided neighbor quads.
// shiftR: value at x-1 (DX=+1 dirs). shiftL: value at x+1 (DX=-1 dirs).
// Strip-wrap lanes inside a wave are exactly image L/R edges -> lm/rm-masked.
__device__ __forceinline__ f4 shiftR4(f4 p, float fixL, bool isLane0) {
    float left = __shfl_up(p.w, 1, 64);
    if (isLane0) left = fixL;        // wave-edge patch
    f4 r; r.x = left; r.y = p.x; r.z = p.y; r.w = p.z; return r;
}
__device__ __forceinline__ f4 shiftL4(f4 p, float fixR, bool isLane63) {
    float right = __shfl_down(p.x, 1, 64);
    if (isLane63) right = fixR;
    f4 r; r.x = p.y; r.y = p.z; r.z = p.w; r.w = right; return r;
}

__device__ __forceinline__ float finish_pixel(float glo, float pmin, int sc,
                                              float t, float cp, float ba, float bb) {
    const float edge = (sc < 8 && sc > 0) ? 1.0f : 0.0f;
    float dec = glo * (1.0f - edge) + (1.0f - pmin) * edge;
    dec = fminf(fmaxf(dec, EPSF), 1.0f - EPSF);
    const float de = -(t * __logf(dec) + (1.0f - t) * __logf(1.0f - dec));
    return de - 0.8f * __logf(cp) - 0.2f * (__logf(ba) + __logf(bb));
}

#define DIR(P, Q, S, DX, RMASK, BI) {                                         \
        f4 s_ = (S);                                                          \
        s_ *= (RMASK);                                                        \
        if ((DX) == 1)  s_.x *= lm;                                           \
        if ((DX) == -1) s_.w *= rm;                                           \
        const f4 v = (P) * s_;                                                \
        glo  = max4(glo,  v);                                                 \
        pmin = min4(pmin, v);                                                 \
        conprod *= sel4((Q), (P), 1.0f - (P));                                \
        BI *= sel4((Q), max4(v, (f4){EPSF,EPSF,EPSF,EPSF}), 1.0f - v);        \
    }

// One row's vote+loss. q loaded in two batches of 4 (peak q-liveness 16 VGPR).
#define ROW(P0,P1,P2,P3,P4,P5,P6,P7, S0,S1,S2,S3,S4,S5,S6,S7, QY, TP, TM, BM) { \
        const int* qy_ = (QY);                                                \
        f4 conprod = {1.f,1.f,1.f,1.f};                                       \
        f4 biA     = {1.f,1.f,1.f,1.f};                                       \
        f4 biB     = {1.f,1.f,1.f,1.f};                                       \
        f4 glo     = {-1e30f,-1e30f,-1e30f,-1e30f};                           \
        f4 pmin    = { 1e30f, 1e30f, 1e30f, 1e30f};                           \
        i4 sc;                                                                \
        {                                                                     \
            const i4 q0 = ldi4(qy_ + 0 * HW);                                 \
            const i4 q1 = ldi4(qy_ + 1 * HW);                                 \
            const i4 q2 = ldi4(qy_ + 2 * HW);                                 \
            const i4 q3 = ldi4(qy_ + 3 * HW);                                 \
            DIR(P0, q0, S0,  1, TM,   biA)                                    \
            DIR(P1, q1, S1,  0, TM,   biA)                                    \
            DIR(P2, q2, S2, -1, TM,   biA)                                    \
            DIR(P3, q3, S3,  1, 1.0f, biA)                                    \
            sc = q0 + q1 + q2 + q3;                                           \
        }                                                                     \
        {                                                                     \
            const i4 q4 = ldi4(qy_ + 4 * HW);                                 \
            const i4 q5 = ldi4(qy_ + 5 * HW);                                 \
            const i4 q6 = ldi4(qy_ + 6 * HW);                                 \
            const i4 q7 = ldi4(qy_ + 7 * HW);                                 \
            DIR(P4, q4, S4, -1, 1.0f, biB)                                    \
            DIR(P5, q5, S5,  1, BM,   biB)                                    \
            DIR(P6, q6, S6,  0, BM,   biB)                                    \
            DIR(P7, q7, S7, -1, BM,   biB)                                    \
            sc += q4 + q5 + q6 + q7;                                          \
        }                                                                     \
        const f4 t4 = ld4(TP);                                                \
        part += finish_pixel(glo.x, pmin.x, sc.x, t4.x, conprod.x, biA.x, biB.x) \
              + finish_pixel(glo.y, pmin.y, sc.y, t4.y, conprod.y, biA.y, biB.y) \
              + finish_pixel(glo.z, pmin.z, sc.z, t4.z, conprod.z, biA.z, biB.z) \
              + finish_pixel(glo.w, pmin.w, sc.w, t4.w, conprod.w, biA.w, biB.w); \
    }

__global__ __launch_bounds__(BLK, 4) void bicon_r14_main(
    const float* __restrict__ c_map,    // [B,8,H,W]
    const float* __restrict__ target,   // [B,1,H,W]
    const int*   __restrict__ con,      // [B,8,H,W] in {0,1}
    float* __restrict__ ws)             // [NBLK] partial sums
{
    const int tid   = blockIdx.x * BLK + threadIdx.x;   // < NT exactly
    const int b     = tid / SPB;
    const int rem   = tid - b * SPB;
    const int strip = rem / W4;
    const int xq    = rem - strip * W4;
    const int x0    = xq * 4;
    const int y0    = strip * RPT;
    const int y1    = y0 + 1;                           // < H always
    const int lane  = threadIdx.x & 63;

    const float* __restrict__ cmb = c_map + (size_t)b * 8 * HW;
    const int*   __restrict__ cnb = con   + (size_t)b * 8 * HW;
    const float* __restrict__ tb  = target + (size_t)b * HW;

    const float lm = (xq == 0)      ? 0.0f : 1.0f;      // left image edge
    const float rm = (xq == W4 - 1) ? 0.0f : 1.0f;      // right image edge
    const int ypr = (y0 > 0)    ? y0 - 1 : 0;           // clamped; tm masks
    const int yn2 = (y1 + 1 < H) ? y1 + 1 : y1;         // clamped; bm masks
    const int xl  = (xq == 0)      ? x0     : x0 - 1;   // lm-masked if edge
    const int xr  = (xq == W4 - 1) ? x0 + 3 : x0 + 4;   // rm-masked if edge

    float part = 0.0f;

    // ---- phase-1 sigmoid working set: 14 quads (56 VGPR) ----
    f4 a5 = sigmoid4(ld4(cmb + 5 * HW + ypr * W + x0));
    f4 a6 = sigmoid4(ld4(cmb + 6 * HW + ypr * W + x0));
    f4 a7 = sigmoid4(ld4(cmb + 7 * HW + ypr * W + x0));
    f4 b0 = sigmoid4(ld4(cmb + 0 * HW + y0 * W + x0));
    f4 b1 = sigmoid4(ld4(cmb + 1 * HW + y0 * W + x0));
    f4 b2 = sigmoid4(ld4(cmb + 2 * HW + y0 * W + x0));
    f4 b3 = sigmoid4(ld4(cmb + 3 * HW + y0 * W + x0));
    f4 b4 = sigmoid4(ld4(cmb + 4 * HW + y0 * W + x0));
    f4 b5 = sigmoid4(ld4(cmb + 5 * HW + y0 * W + x0));
    f4 b6 = sigmoid4(ld4(cmb + 6 * HW + y0 * W + x0));
    f4 b7 = sigmoid4(ld4(cmb + 7 * HW + y0 * W + x0));
    f4 c0 = sigmoid4(ld4(cmb + 0 * HW + y1 * W + x0));
    f4 c1 = sigmoid4(ld4(cmb + 1 * HW + y1 * W + x0));
    f4 c2 = sigmoid4(ld4(cmb + 2 * HW + y1 * W + x0));

    // ---------------- row y0 ----------------
    {
        float fA = 0.f, fB = 0.f, fC = 0.f, fD = 0.f, fE = 0.f, fF = 0.f;
        if (lane == 0) {
            fA = sigf(cmb[7 * HW + ypr * W + xl]);
            fB = sigf(cmb[4 * HW + y0  * W + xl]);
            fC = sigf(cmb[2 * HW + y1  * W + xl]);
        } else if (lane == 63) {
            fD = sigf(cmb[5 * HW + ypr * W + xr]);
            fE = sigf(cmb[3 * HW + y0  * W + xr]);
            fF = sigf(cmb[0 * HW + y1  * W + xr]);
        }
        const float tm = (y0 == 0) ? 0.0f : 1.0f;       // bm=1 (y0 even < H-1)
        const f4 s0 = shiftR4(a7, fA, lane == 0);       // ch7 @ (y0-1, x-1)
        const f4 s1 = a6;                               // ch6 @ (y0-1, x  )
        const f4 s2 = shiftL4(a5, fD, lane == 63);      // ch5 @ (y0-1, x+1)
        const f4 s3 = shiftR4(b4, fB, lane == 0);       // ch4 @ (y0,   x-1)
        const f4 s4 = shiftL4(b3, fE, lane == 63);      // ch3 @ (y0,   x+1)
        const f4 s5 = shiftR4(c2, fC, lane == 0);       // ch2 @ (y0+1, x-1)
        const f4 s6 = c1;                               // ch1 @ (y0+1, x  )
        const f4 s7 = shiftL4(c0, fF, lane == 63);      // ch0 @ (y0+1, x+1)
        ROW(b0,b1,b2,b3,b4,b5,b6,b7, s0,s1,s2,s3,s4,s5,s6,s7,
            cnb + y0 * W + x0, tb + y0 * W + x0, tm, 1.0f)
    }

    // ---------------- row y1 ----------------
    {
        // B-role @ y1: have c0,c1,c2; load ch3..7. C-role @ yn2: ch0..2.
        f4 d3 = sigmoid4(ld4(cmb + 3 * HW + y1 * W + x0));
        f4 d4 = sigmoid4(ld4(cmb + 4 * HW + y1 * W + x0));
        f4 d5 = sigmoid4(ld4(cmb + 5 * HW + y1 * W + x0));
        f4 d6 = sigmoid4(ld4(cmb + 6 * HW + y1 * W + x0));
        f4 d7 = sigmoid4(ld4(cmb + 7 * HW + y1 * W + x0));
        f4 e0 = sigmoid4(ld4(cmb + 0 * HW + yn2 * W + x0));
        f4 e1 = sigmoid4(ld4(cmb + 1 * HW + yn2 * W + x0));
        f4 e2 = sigmoid4(ld4(cmb + 2 * HW + yn2 * W + x0));

        float fA = 0.f, fB = 0.f, fC = 0.f, fD = 0.f, fE = 0.f, fF = 0.f;
        if (lane == 0) {
            fA = sigf(cmb[7 * HW + y0  * W + xl]);
            fB = sigf(cmb[4 * HW + y1  * W + xl]);
            fC = sigf(cmb[2 * HW + yn2 * W + xl]);
        } else if (lane == 63) {
            fD = sigf(cmb[5 * HW + y0  * W + xr]);
            fE = sigf(cmb[3 * HW + y1  * W + xr]);
            fF = sigf(cmb[0 * HW + yn2 * W + xr]);
        }
        const float bm = (y1 == H - 1) ? 0.0f : 1.0f;   // tm=1 (y1 odd > 0)
        const f4 s0 = shiftR4(b7, fA, lane == 0);       // ch7 @ (y0,   x-1)
        const f4 s1 = b6;                               // ch6 @ (y0,   x  )
        const f4 s2 = shiftL4(b5, fD, lane == 63);      // ch5 @ (y0,   x+1)
        const f4 s3 = shiftR4(d4, fB, lane == 0);       // ch4 @ (y1,   x-1)
        const f4 s4 = shiftL4(d3, fE, lane == 63);      // ch3 @ (y1,   x+1)
        const f4 s5 = shiftR4(e2, fC, lane == 0);       // ch2 @ (y1+1, x-1)
        const f4 s6 = e1;                               // ch1 @ (y1+1, x  )
        const f4 s7 = shiftL4(e0, fF, lane == 63);      // ch0 @ (y1+1, x+1)
        ROW(c0,c1,c2,d3,d4,d5,d6,d7, s0,s1,s2,s3,s4,s5,s6,s7,
            cnb + y1 * W + x0, tb + y1 * W + x0, 1.0f, bm)
    }

    // wave64 shuffle reduction
    #pragma unroll
    for (int off = 32; off > 0; off >>= 1)
        part += __shfl_down(part, off, 64);

    __shared__ float wsum[4];
    const int wid = threadIdx.x >> 6;
    if (lane == 0) wsum[wid] = part;
    __syncthreads();
    if (threadIdx.x == 0) {
        ws[blockIdx.x] = wsum[0] + wsum[1] + wsum[2] + wsum[3];  // plain store
    }
}

// Stage 2: one block sums the NBLK partials and writes the scalar output.
__global__ __launch_bounds__(256) void bicon_r14_reduce(
    const float* __restrict__ ws, float* __restrict__ out)
{
    float s = 0.0f;
    for (int i = threadIdx.x; i < NBLK; i += 256) s += ws[i];
    #pragma unroll
    for (int off = 32; off > 0; off >>= 1)
        s += __shfl_down(s, off, 64);
    __shared__ float wsum[4];
    const int lane = threadIdx.x & 63;
    const int wid  = threadIdx.x >> 6;
    if (lane == 0) wsum[wid] = s;
    __syncthreads();
    if (threadIdx.x == 0) out[0] = wsum[0] + wsum[1] + wsum[2] + wsum[3];
}

extern "C" void kernel_launch(void* const* d_in, const int* in_sizes, int n_in,
                              void* d_out, int out_size, void* d_ws, size_t ws_size,
                              hipStream_t stream) {
    const float* c_map  = (const float*)d_in[0];
    const float* target = (const float*)d_in[1];
    const int*   con    = (const int*)d_in[2];
    float* out = (float*)d_out;
    float* ws  = (float*)d_ws;   // NBLK floats

    bicon_r14_main<<<NBLK, BLK, 0, stream>>>(c_map, target, con, ws);
    bicon_r14_reduce<<<1, 256, 0, stream>>>(ws, out);
}

// Round 9
// 156.059 us; speedup vs baseline: 1.1316x; 1.1316x over previous
//
#include <hip/hip_runtime.h>

// bicon_loss R15: byte reduction via LDS staging (registers were a dead end).
// R13: 184 VGPR -> 2 waves/SIMD -> 64us. R14: forced 64 VGPR -> 48.5MB spill
// traffic -> 74us. Session facts: (a) dispatches with hbm_bytes=63KB (fully
// L3-resident) run at the SAME 46us as 74MB ones -> duration insensitive to
// service level; (b) forced 25-outstanding burst flat -> MLP not the limit.
// Model: per-CU outstanding-line cap drains the request stream at ~4.3 TB/s;
// only lever left is request BYTES. R15: block=704 threads (11 waves) owns an
// 8x352 slab; sigmoid(c_map) staged ONCE into 60.5KB LDS (2 phases reusing
// the buffer: A=ch5-7 rows -1..7 + ch3-4 rows 0..7; B=ch0-2 rows 0..8).
// Neighbors = LDS quad reads + 1-float fixups. 71 B/px vs R6's 100 (-29%),
// sigmoid work -37%, per-thread state ~50 floats (no spill risk).
// Canaries: LDS_Block_Size ~60544; WRITE_SIZE <1MB (spill); VGPR 96-128.
// Prediction: main 46 -> 33-40us. Flat at >=45us with no spill => byte lever
// falsified => structural cap, declare next round.

#define EPSF 1e-7f

constexpr int B_ = 16, H = 352, W = 352;
constexpr int HW = H * W;            // 123904
constexpr int W4 = 88;               // quads per row
constexpr int RPB = 8;               // rows per block
constexpr int BLK = 704;             // 11 waves, = 8*88 quads
constexpr int STRIPS = H / RPB;      // 44
constexpr int NBLK = B_ * STRIPS;    // 704
constexpr int PLN = 352;             // floats per LDS plane (88 quads)
constexpr int NPLANE_A = 43;         // ch5,6,7 x rows -1..7 (27) + ch3,4 x rows 0..7 (16)
constexpr int NPLANE_B = 27;         // ch0,1,2 x rows 0..8
constexpr int SLOTS_A = NPLANE_A * W4;   // 3784
constexpr int SLOTS_B = NPLANE_B * W4;   // 2376

typedef float f4 __attribute__((ext_vector_type(4)));
typedef int   i4 __attribute__((ext_vector_type(4)));

__device__ __forceinline__ float rcpf(float x) { return __builtin_amdgcn_rcpf(x); }

__device__ __forceinline__ f4 sigmoid4(f4 x) {
    f4 r;
    r.x = rcpf(1.0f + __expf(-x.x));
    r.y = rcpf(1.0f + __expf(-x.y));
    r.z = rcpf(1.0f + __expf(-x.z));
    r.w = rcpf(1.0f + __expf(-x.w));
    return r;
}
__device__ __forceinline__ f4 max4(f4 a, f4 b) {
    f4 r; r.x=fmaxf(a.x,b.x); r.y=fmaxf(a.y,b.y); r.z=fmaxf(a.z,b.z); r.w=fmaxf(a.w,b.w); return r;
}
__device__ __forceinline__ f4 min4(f4 a, f4 b) {
    f4 r; r.x=fminf(a.x,b.x); r.y=fminf(a.y,b.y); r.z=fminf(a.z,b.z); r.w=fminf(a.w,b.w); return r;
}
__device__ __forceinline__ f4 sel4(i4 q, f4 a, f4 b) {
    f4 r; r.x=q.x?a.x:b.x; r.y=q.y?a.y:b.y; r.z=q.z?a.z:b.z; r.w=q.w?a.w:b.w; return r;
}
__device__ __forceinline__ f4 ld4(const float* p) { return *(const f4*)p; }
__device__ __forceinline__ i4 ldi4(const int* p)  { return *(const i4*)p; }

__device__ __forceinline__ float finish_pixel(float glo, float pmin, int sc,
                                              float t, float cp, float ba, float bb) {
    const float edge = (sc < 8 && sc > 0) ? 1.0f : 0.0f;
    float dec = glo * (1.0f - edge) + (1.0f - pmin) * edge;
    dec = fminf(fmaxf(dec, EPSF), 1.0f - EPSF);
    const float de = -(t * __logf(dec) + (1.0f - t) * __logf(1.0f - dec));
    return de - 0.8f * __logf(cp) - 0.2f * (__logf(ba) + __logf(bb));
}

#define DIR(P, Q, S, DX, RMASK, BI) {                                         \
        f4 s_ = (S);                                                          \
        s_ *= (RMASK);                                                        \
        if ((DX) == 1)  s_.x *= lm;                                           \
        if ((DX) == -1) s_.w *= rm;                                           \
        const f4 v = (P) * s_;                                                \
        glo  = max4(glo,  v);                                                 \
        pmin = min4(pmin, v);                                                 \
        conprod *= sel4((Q), (P), 1.0f - (P));                                \
        BI *= sel4((Q), max4(v, (f4){EPSF,EPSF,EPSF,EPSF}), 1.0f - v);        \
    }

__global__ __launch_bounds__(BLK) void bicon_r15_main(
    const float* __restrict__ c_map,    // [B,8,H,W]
    const float* __restrict__ target,   // [B,1,H,W]
    const int*   __restrict__ con,      // [B,8,H,W] in {0,1}
    float* __restrict__ ws)             // [NBLK] partial sums
{
    __shared__ float lds[NPLANE_A * PLN];   // 60544 B, reused by phase B

    const int bi    = blockIdx.x;
    const int b     = bi / STRIPS;
    const int strip = bi - b * STRIPS;
    const int ty0   = strip * RPB;
    const int tid   = threadIdx.x;
    const int row   = tid / W4;          // 0..7
    const int qc    = tid - row * W4;    // 0..87
    const int x0    = qc * 4;
    const int y     = ty0 + row;

    const float* __restrict__ cmb = c_map + (size_t)b * 8 * HW;
    const int*   __restrict__ cnb = con   + (size_t)b * 8 * HW;
    const float* __restrict__ tb  = target + (size_t)b * HW;

    // ---------------- phase A stage: ch5,6,7 rows -1..7, ch3,4 rows 0..7 ----
    #pragma unroll
    for (int k = 0; k < 6; ++k) {
        const int s = tid + k * BLK;
        if (s < SLOTS_A) {
            const int plane = s / W4;
            const int qs    = s - plane * W4;
            int ch, r;
            if (plane < 27) { ch = 5 + plane / 9; r = plane % 9 - 1; }
            else            { const int p2 = plane - 27; ch = 3 + (p2 >> 3); r = p2 & 7; }
            int g = ty0 + r; g = (g < 0) ? 0 : ((g > H - 1) ? H - 1 : g);
            const f4 v = sigmoid4(ld4(cmb + ch * HW + g * W + qs * 4));
            *(f4*)&lds[plane * PLN + qs * 4] = v;
        }
    }
    // q3,q4,t in flight across the barrier (used in phase A compute)
    const i4 q3 = ldi4(cnb + 3 * HW + y * W + x0);
    const i4 q4 = ldi4(cnb + 4 * HW + y * W + x0);
    const f4 t4 = ld4(tb + y * W + x0);
    __syncthreads();

    // ---------------- phase A compute: S0-S2 saved, dirs 3,4 done ----------
    const float lm = (qc == 0)      ? 0.0f : 1.0f;
    const float rm = (qc == W4 - 1) ? 0.0f : 1.0f;
    const float tm = (y == 0)       ? 0.0f : 1.0f;
    const float bm = (y == H - 1)   ? 0.0f : 1.0f;
    const int xl = (x0 > 0) ? x0 - 1 : 0;        // lm-masked when clamped
    const int xr = (x0 + 4 < W) ? x0 + 4 : W - 1; // rm-masked when clamped

    // plane maps (phase A): ch5 -> (r+1), ch6 -> 9+(r+1), ch7 -> 18+(r+1),
    //                       ch3 -> 27+r,  ch4 -> 35+r
    f4 C;
    C = *(const f4*)&lds[(18 + row) * PLN + x0];                // ch7 @ row-1
    f4 S0 = {lds[(18 + row) * PLN + xl], C.x, C.y, C.z};
    f4 S1 = *(const f4*)&lds[(9 + row) * PLN + x0];             // ch6 @ row-1
    C = *(const f4*)&lds[(0 + row) * PLN + x0];                 // ch5 @ row-1
    f4 S2 = {C.y, C.z, C.w, lds[(0 + row) * PLN + xr]};
    const f4 p5 = *(const f4*)&lds[(0 + row + 1) * PLN + x0];
    const f4 p6 = *(const f4*)&lds[(9 + row + 1) * PLN + x0];
    const f4 p7 = *(const f4*)&lds[(18 + row + 1) * PLN + x0];
    const f4 p3 = *(const f4*)&lds[(27 + row) * PLN + x0];
    const f4 p4 = *(const f4*)&lds[(35 + row) * PLN + x0];
    const f4 S3 = {lds[(35 + row) * PLN + xl], p4.x, p4.y, p4.z}; // ch4 @ (y,x-1)
    const f4 S4 = {p3.y, p3.z, p3.w, lds[(27 + row) * PLN + xr]}; // ch3 @ (y,x+1)

    f4 conprod = {1.f,1.f,1.f,1.f};
    f4 biA     = {1.f,1.f,1.f,1.f};
    f4 biB     = {1.f,1.f,1.f,1.f};
    f4 glo     = {-1e30f,-1e30f,-1e30f,-1e30f};
    f4 pmin    = { 1e30f, 1e30f, 1e30f, 1e30f};

    DIR(p3, q3, S3,  1, 1.0f, biA)
    DIR(p4, q4, S4, -1, 1.0f, biB)
    i4 sc = q3 + q4;

    __syncthreads();   // phase A reads done before LDS reuse

    // ---------------- phase B stage: ch0,1,2 rows 0..8 ---------------------
    #pragma unroll
    for (int k = 0; k < 4; ++k) {
        const int s = tid + k * BLK;
        if (s < SLOTS_B) {
            const int plane = s / W4;
            const int qs    = s - plane * W4;
            const int ch = plane / 9;
            const int r  = plane - ch * 9;      // 0..8
            int g = ty0 + r; g = (g > H - 1) ? H - 1 : g;
            const f4 v = sigmoid4(ld4(cmb + ch * HW + g * W + qs * 4));
            *(f4*)&lds[plane * PLN + qs * 4] = v;
        }
    }
    // remaining q in flight across the barrier
    const i4 q0 = ldi4(cnb + 0 * HW + y * W + x0);
    const i4 q1 = ldi4(cnb + 1 * HW + y * W + x0);
    const i4 q2 = ldi4(cnb + 2 * HW + y * W + x0);
    const i4 q5 = ldi4(cnb + 5 * HW + y * W + x0);
    const i4 q6 = ldi4(cnb + 6 * HW + y * W + x0);
    const i4 q7 = ldi4(cnb + 7 * HW + y * W + x0);
    __syncthreads();

    // ---------------- phase B compute: dirs 0,1,2,5,6,7 --------------------
    // plane maps (phase B): ch0 -> r, ch1 -> 9+r, ch2 -> 18+r  (r = 0..8)
    const f4 p0 = *(const f4*)&lds[(0 + row) * PLN + x0];
    const f4 p1 = *(const f4*)&lds[(9 + row) * PLN + x0];
    const f4 p2 = *(const f4*)&lds[(18 + row) * PLN + x0];
    C = *(const f4*)&lds[(18 + row + 1) * PLN + x0];            // ch2 @ row+1
    const f4 S5 = {lds[(18 + row + 1) * PLN + xl], C.x, C.y, C.z};
    const f4 S6 = *(const f4*)&lds[(9 + row + 1) * PLN + x0];   // ch1 @ row+1
    C = *(const f4*)&lds[(0 + row + 1) * PLN + x0];             // ch0 @ row+1
    const f4 S7 = {C.y, C.z, C.w, lds[(0 + row + 1) * PLN + xr]};

    DIR(p0, q0, S0,  1, tm, biA)
    DIR(p1, q1, S1,  0, tm, biA)
    DIR(p2, q2, S2, -1, tm, biA)
    DIR(p5, q5, S5,  1, bm, biB)
    DIR(p6, q6, S6,  0, bm, biB)
    DIR(p7, q7, S7, -1, bm, biB)
    sc += q0 + q1 + q2 + q5 + q6 + q7;

    float part = finish_pixel(glo.x, pmin.x, sc.x, t4.x, conprod.x, biA.x, biB.x)
               + finish_pixel(glo.y, pmin.y, sc.y, t4.y, conprod.y, biA.y, biB.y)
               + finish_pixel(glo.z, pmin.z, sc.z, t4.z, conprod.z, biA.z, biB.z)
               + finish_pixel(glo.w, pmin.w, sc.w, t4.w, conprod.w, biA.w, biB.w);

    // wave64 shuffle reduction (11 waves)
    #pragma unroll
    for (int off = 32; off > 0; off >>= 1)
        part += __shfl_down(part, off, 64);

    __shared__ float wsum[11];
    const int lane = tid & 63;
    const int wid  = tid >> 6;
    if (lane == 0) wsum[wid] = part;
    __syncthreads();
    if (tid == 0) {
        float s = 0.0f;
        #pragma unroll
        for (int w = 0; w < 11; ++w) s += wsum[w];
        ws[bi] = s;                                  // plain store
    }
}

// Stage 2: one block sums the NBLK partials and writes the scalar output.
__global__ __launch_bounds__(256) void bicon_r15_reduce(
    const float* __restrict__ ws, float* __restrict__ out)
{
    float s = 0.0f;
    for (int i = threadIdx.x; i < NBLK; i += 256) s += ws[i];
    #pragma unroll
    for (int off = 32; off > 0; off >>= 1)
        s += __shfl_down(s, off, 64);
    __shared__ float wsum[4];
    const int lane = threadIdx.x & 63;
    const int wid  = threadIdx.x >> 6;
    if (lane == 0) wsum[wid] = s;
    __syncthreads();
    if (threadIdx.x == 0) out[0] = wsum[0] + wsum[1] + wsum[2] + wsum[3];
}

extern "C" void kernel_launch(void* const* d_in, const int* in_sizes, int n_in,
                              void* d_out, int out_size, void* d_ws, size_t ws_size,
                              hipStream_t stream) {
    const float* c_map  = (const float*)d_in[0];
    const float* target = (const float*)d_in[1];
    const int*   con    = (const int*)d_in[2];
    float* out = (float*)d_out;
    float* ws  = (float*)d_ws;   // NBLK floats

    bicon_r15_main<<<NBLK, BLK, 0, stream>>>(c_map, target, con, ws);
    bicon_r15_reduce<<<1, 256, 0, stream>>>(ws, out);
}